// Round 12
// baseline (314.051 us; speedup 1.0000x reference)
//
#include <hip/hip_runtime.h>
#include <hip/hip_bf16.h>
#include <cstdint>

#define E_N   512
#define C_N   64
#define HW_N  784
#define CHW_N 50176     // C_N * HW_N
#define CHW4  12544
#define NC    256
#define GHW   28        // hw-chunk for fused gmax-reduce+g4

typedef __attribute__((ext_vector_type(8))) short bf16x8;
typedef __attribute__((ext_vector_type(4))) float f32x4;
typedef __attribute__((ext_vector_type(8))) unsigned short us8;

// exact RNE f32 -> bf16 (no NaN inputs here)
__device__ __forceinline__ unsigned short bf16_rne(float f, float& hif) {
    unsigned int u = __float_as_uint(f);
    unsigned int r = u + 0x7FFFu + ((u >> 16) & 1u);
    unsigned short h = (unsigned short)(r >> 16);
    hif = __uint_as_float((unsigned int)h << 16);
    return h;
}

// 8 f32 -> bf16x8 hi + bf16x8 lo, all in registers (RNE via v_cvt_pk_bf16_f32)
__device__ __forceinline__ void cvt8(const float* f, bf16x8& hi, bf16x8& lo) {
    unsigned int hw_[4], lw_[4];
    #pragma unroll
    for (int p = 0; p < 4; ++p) {
        float a = f[2 * p], b = f[2 * p + 1];
        unsigned int hp;
        asm("v_cvt_pk_bf16_f32 %0, %1, %2" : "=v"(hp) : "v"(a), "v"(b));
        float ha = __uint_as_float(hp << 16);
        float hb = __uint_as_float(hp & 0xFFFF0000u);
        float la = a - ha, lb = b - hb;
        unsigned int lp;
        asm("v_cvt_pk_bf16_f32 %0, %1, %2" : "=v"(lp) : "v"(la), "v"(lb));
        hw_[p] = hp; lw_[p] = lp;
    }
    union { unsigned int u[4]; bf16x8 v; } cu, cl;
    #pragma unroll
    for (int p = 0; p < 4; ++p) { cu.u[p] = hw_[p]; cl.u[p] = lw_[p]; }
    hi = cu.v; lo = cl.v;
}

// ---------------- kernel 1: CSR adjacency + inv_count + W split (bf16 hi/lo) --
__global__ void prep_k(const int* __restrict__ ec, const float* __restrict__ W,
                       int* __restrict__ adj_start, int* __restrict__ adj_edge,
                       float* __restrict__ inv_count,
                       unsigned short* __restrict__ Whi, unsigned short* __restrict__ Wlo)
{
    __shared__ int cnt[NC];
    __shared__ int st[NC + 1];
    int tid = threadIdx.x;
    if (tid < NC) cnt[tid] = 0;
    __syncthreads();
    for (int e = tid; e < E_N; e += 256) {
        atomicAdd(&cnt[ec[2 * e] & (NC - 1)], 1);
        atomicAdd(&cnt[ec[2 * e + 1] & (NC - 1)], 1);
    }
    __syncthreads();
    // parallel prefix scan over 256 counts: wave 0, 4 values/lane
    if (tid < 64) {
        int b = tid * 4;
        int v0 = cnt[b], v1 = cnt[b + 1], v2 = cnt[b + 2], v3 = cnt[b + 3];
        int s4 = v0 + v1 + v2 + v3;
        int incl = s4;
        #pragma unroll
        for (int off = 1; off < 64; off <<= 1) {
            int t = __shfl_up(incl, off);
            if (tid >= off) incl += t;
        }
        int ex = incl - s4;
        st[b] = ex; st[b + 1] = ex + v0; st[b + 2] = ex + v0 + v1; st[b + 3] = ex + v0 + v1 + v2;
        if (tid == 63) st[NC] = incl;
    }
    __syncthreads();
    if (tid < NC) {
        adj_start[tid] = st[tid];
        inv_count[tid] = 1.0f / (float)((cnt[tid] > 1) ? cnt[tid] : 1);
        cnt[tid] = st[tid];
    }
    if (tid == 0) adj_start[NC] = st[NC];
    __syncthreads();
    for (int e = tid; e < E_N; e += 256) {
        adj_edge[atomicAdd(&cnt[ec[2 * e] & (NC - 1)], 1)] = e;
        adj_edge[atomicAdd(&cnt[ec[2 * e + 1] & (NC - 1)], 1)] = e;
    }
    // split first 192 cols of W_agg (row-major [o][256]) into bf16 hi/lo [o][192]
    for (int i = tid; i < 64 * 192; i += 256) {
        int o = i / 192, k = i - o * 192;
        float w = W[o * 256 + k];
        float hif;
        unsigned short hi = bf16_rne(w, hif);
        float d;
        unsigned short lo = bf16_rne(w - hif, d);
        Whi[i] = hi;
        Wlo[i] = lo;
    }
}

// ---------------- kernel 2: global max over edges, partial (8 chunks), f4 ----
__global__ void gmax_part_k(const float* __restrict__ x, float* __restrict__ part)
{
    int p4 = blockIdx.x * 256 + threadIdx.x;
    const float4* p = reinterpret_cast<const float4*>(x) + (size_t)(blockIdx.y * 64) * CHW4 + p4;
    float4 m = make_float4(-INFINITY, -INFINITY, -INFINITY, -INFINITY);
    #pragma unroll 4
    for (int i = 0; i < 64; ++i) {
        float4 v = p[(size_t)i * CHW4];
        m.x = fmaxf(m.x, v.x); m.y = fmaxf(m.y, v.y);
        m.z = fmaxf(m.z, v.z); m.w = fmaxf(m.w, v.w);
    }
    reinterpret_cast<float4*>(part)[blockIdx.y * CHW4 + p4] = m;
}

// ---------------- kernel 3: fused reduce(8 partials) + G4 GEMV ---------------
// block b owns hw in [b*GHW, (b+1)*GHW); phase1: gmax tile to LDS; phase2:
// g4[o,hw] = sum_c W4[o][c] * gm[c][hw].  grid = 784/GHW = 28 blocks.
__global__ void g4r_k(const float* __restrict__ part, const float* __restrict__ W,
                      float* __restrict__ g4)
{
    __shared__ float gm[64][GHW];
    int tid = threadIdx.x;
    int hw0 = blockIdx.x * GHW;
    #pragma unroll
    for (int k = 0; k < 7; ++k) {
        int idx = tid + k * 256;            // 0..1791 = 64*28
        int c = idx / GHW, hw = idx - c * GHW;
        float m = -INFINITY;
        #pragma unroll
        for (int i = 0; i < 8; ++i)
            m = fmaxf(m, part[(size_t)i * CHW_N + c * HW_N + hw0 + hw]);
        gm[c][hw] = m;
    }
    __syncthreads();
    #pragma unroll
    for (int k = 0; k < 7; ++k) {
        int idx = tid + k * 256;
        int o = idx / GHW, hw = idx - o * GHW;
        float acc = 0.f;
        #pragma unroll 8
        for (int c = 0; c < 64; ++c)
            acc += W[o * 256 + 192 + c] * gm[c][hw];
        g4[o * HW_N + hw0 + hw] = acc;
    }
}

// ---------------- kernel 4: corner features (segment mean, fp32) -------------
__global__ void cf_k(const float* __restrict__ x, const int* __restrict__ adj_start,
                     const int* __restrict__ adj_edge, const float* __restrict__ inv_count,
                     float* __restrict__ cf)
{
    int c  = blockIdx.y;
    int p4 = blockIdx.x * 256 + threadIdx.x;
    float4 acc = make_float4(0.f, 0.f, 0.f, 0.f);
    int s0 = adj_start[c], s1 = adj_start[c + 1];
    for (int i = s0; i < s1; ++i) {
        int e = adj_edge[i];
        float4 v = *reinterpret_cast<const float4*>(x + (size_t)e * CHW_N + (size_t)p4 * 4);
        acc.x += v.x; acc.y += v.y; acc.z += v.z; acc.w += v.w;
    }
    float ic = inv_count[c];
    acc.x *= ic; acc.y *= ic; acc.z *= ic; acc.w *= ic;
    *reinterpret_cast<float4*>(cf + (size_t)c * CHW_N + (size_t)p4 * 4) = acc;
}

// ---------------- kernel 5: fused MFMA matmul (split-bf16) + G4 + relu -------
// out[o, j] = relu( sum_{k<192} W[o][k] * B[k][j] + G4[o, hw(j)] )
// R9 post-mortem: latency-bound (39% busy, occ 27%, VGPR 68 = no pipelining).
// R10: Ah-only LDS (25.8KB -> more blocks/CU), Al frags direct from global
// (L2-hot 24KB), launch_bounds(256,4) for VGPR 128, explicit B ping-pong
// prefetch, per-thread (e,hw,c0,c1) so first B load issues before staging.
__global__ __launch_bounds__(256, 4) void fused_mfma_k(
    const float* __restrict__ x, const float* __restrict__ cf,
    const unsigned short* __restrict__ Whi, const unsigned short* __restrict__ Wlo,
    const float* __restrict__ g4, const int* __restrict__ ec,
    float* __restrict__ out)
{
    __shared__ unsigned short Ah[64][200];   // 25.6 KB

    int tid  = threadIdx.x;
    int lane = tid & 63;
    int wv   = tid >> 6;
    int r16  = lane & 15;
    int q    = lane >> 4;
    int jbase = blockIdx.x * 128;

    // per-thread j-group info for this wave's two 16-col groups
    int j16a = jbase + (wv * 2) * 16;
    int ea   = j16a / HW_N;
    int hwa  = j16a - ea * HW_N;
    int j16b = j16a + 16;
    int eb   = j16b / HW_N;
    int hwb  = j16b - eb * HW_N;
    int c0a = ec[2 * ea] & (NC - 1), c1a = ec[2 * ea + 1] & (NC - 1);
    int c0b = ec[2 * eb] & (NC - 1), c1b = ec[2 * eb + 1] & (NC - 1);

    // per-lane global bases for B fragments (j = r16 in group, k = q*8)
    const float* pB0[3];
    const float* pB1[3];
    pB0[0] = x  + (size_t)ea  * CHW_N + hwa + q * 8 * HW_N + r16;
    pB1[0] = x  + (size_t)eb  * CHW_N + hwb + q * 8 * HW_N + r16;
    pB0[1] = cf + (size_t)c0a * CHW_N + hwa + q * 8 * HW_N + r16;
    pB1[1] = cf + (size_t)c0b * CHW_N + hwb + q * 8 * HW_N + r16;
    pB0[2] = cf + (size_t)c1a * CHW_N + hwa + q * 8 * HW_N + r16;
    pB1[2] = cf + (size_t)c1b * CHW_N + hwb + q * 8 * HW_N + r16;

    // issue first B tile load immediately (overlaps Ah staging + barrier)
    float fa[8], fb[8], ga[8], gb[8];
    #pragma unroll
    for (int i = 0; i < 8; ++i) fa[i] = pB0[0][i * HW_N];
    #pragma unroll
    for (int i = 0; i < 8; ++i) fb[i] = pB1[0][i * HW_N];

    // stage Ah (W hi, 64 x 192) once
    #pragma unroll
    for (int i = 0; i < 6; ++i) {
        int chunk = tid + i * 256;           // 0..1535
        int row = chunk / 24, c8 = chunk % 24;
        *reinterpret_cast<us8*>(&Ah[row][c8 * 8]) =
            *reinterpret_cast<const us8*>(Whi + row * 192 + c8 * 8);
    }
    __syncthreads();

    // per-lane base into Wlo for al fragments
    const unsigned short* pAl = Wlo + r16 * 192 + q * 8;

    f32x4 acc[4][2];
    #pragma unroll
    for (int a = 0; a < 4; ++a)
        #pragma unroll
        for (int b = 0; b < 2; ++b) acc[a][b] = (f32x4){0.f, 0.f, 0.f, 0.f};

    #pragma unroll
    for (int s = 0; s < 6; ++s) {
        const int k0 = s * 32;
        float* c0 = (s & 1) ? ga : fa;
        float* c1 = (s & 1) ? gb : fb;
        float* n0 = (s & 1) ? fa : ga;
        float* n1 = (s & 1) ? fb : gb;
        if (s < 5) {
            const int nseg = (s + 1) >> 1, nkr = ((s + 1) & 1) * 32;
            #pragma unroll
            for (int i = 0; i < 8; ++i) n0[i] = pB0[nseg][(nkr + i) * HW_N];
            #pragma unroll
            for (int i = 0; i < 8; ++i) n1[i] = pB1[nseg][(nkr + i) * HW_N];
        }

        // A frags: hi from LDS, lo direct from global (L2-hot)
        bf16x8 ah[4], al[4];
        #pragma unroll
        for (int ot = 0; ot < 4; ++ot) {
            ah[ot] = *reinterpret_cast<const bf16x8*>(&Ah[ot * 16 + r16][k0 + q * 8]);
            al[ot] = *reinterpret_cast<const bf16x8*>(pAl + (ot * 16) * 192 + k0);
        }

        // convert current B in registers
        bf16x8 bh[2], bl[2];
        cvt8(c0, bh[0], bl[0]);
        cvt8(c1, bh[1], bl[1]);

        // 24 MFMAs: 4 o-tiles x 2 j-tiles x 3 splits
        #pragma unroll
        for (int ot = 0; ot < 4; ++ot)
            #pragma unroll
            for (int jt = 0; jt < 2; ++jt) {
                acc[ot][jt] = __builtin_amdgcn_mfma_f32_16x16x32_bf16(ah[ot], bh[jt], acc[ot][jt], 0, 0, 0);
                acc[ot][jt] = __builtin_amdgcn_mfma_f32_16x16x32_bf16(ah[ot], bl[jt], acc[ot][jt], 0, 0, 0);
                acc[ot][jt] = __builtin_amdgcn_mfma_f32_16x16x32_bf16(al[ot], bh[jt], acc[ot][jt], 0, 0, 0);
            }
    }

    // epilogue: + G4, relu, store (D: col=lane&15, row=(lane>>4)*4+reg)
    int orb = q << 2;
    #pragma unroll
    for (int ot = 0; ot < 4; ++ot)
        #pragma unroll
        for (int jt = 0; jt < 2; ++jt) {
            int e  = jt ? eb : ea;
            int hw = (jt ? hwb : hwa) + r16;
            #pragma unroll
            for (int r = 0; r < 4; ++r) {
                int o = ot * 16 + orb + r;
                float v = acc[ot][jt][r] + g4[o * HW_N + hw];
                out[(size_t)e * CHW_N + o * HW_N + hw] = fmaxf(v, 0.f);
            }
        }
}

// ---------------- launch ----------------
extern "C" void kernel_launch(void* const* d_in, const int* in_sizes, int n_in,
                              void* d_out, int out_size, void* d_ws, size_t ws_size,
                              hipStream_t stream)
{
    const float* x  = (const float*)d_in[0];
    const float* W  = (const float*)d_in[1];
    const int*   ec = (const int*)d_in[3];    // edge_corner (E,2) int32
    float* out      = (float*)d_out;

    // workspace layout (floats)
    float* ws_f      = (float*)d_ws;
    float* cf        = ws_f;                        // 12,845,056
    float* part      = cf + (size_t)NC * CHW_N;     // 401,408
    float* g4        = part + 8 * CHW_N;            // 50,176
    unsigned short* Whi = (unsigned short*)(g4 + CHW_N);  // 12,288 us
    unsigned short* Wlo = Whi + 12288;                    // 12,288 us
    int*   adj_start = (int*)(Wlo + 12288);         // 257 (pad 272)
    int*   adj_edge  = adj_start + 272;             // 1024
    float* inv_count = (float*)(adj_edge + 1024);   // 256

    prep_k<<<1, 256, 0, stream>>>(ec, W, adj_start, adj_edge, inv_count, Whi, Wlo);
    gmax_part_k<<<dim3(49, 8), 256, 0, stream>>>(x, part);
    g4r_k<<<28, 256, 0, stream>>>(part, W, g4);
    cf_k<<<dim3(49, NC), 256, 0, stream>>>(x, adj_start, adj_edge, inv_count, cf);
    fused_mfma_k<<<3136, 256, 0, stream>>>(x, cf, Whi, Wlo, g4, ec, out);
}